// Round 1
// baseline (618.915 us; speedup 1.0000x reference)
//
#include <hip/hip_runtime.h>
#include <hip/hip_cooperative_groups.h>
#include <stdint.h>

namespace cg = cooperative_groups;

// BoltzmannGateSTE: out = x * (|x| >= T), T = k-th largest |x|, k = int(n/e).
// Fast path = ONE cooperative kernel (1024 blocks co-resident, 4/CU):
//   phase 1: stream x -> out with bracket [LO,HI) = [0.88,0.92):
//     u >= HI -> keep, tally chi;  u < LO -> zero;
//     else candidate -> placeholder 0, ballot-compacted into a per-wave LDS
//     buffer (512 slots, mean ~174, 26 sigma), and ONE fire-and-forget global
//     atomicAdd into the exact per-bit-pattern table fineH[u - LO].
//   grid.sync
//   phase 2: blocks 0..655 build 656-bin coarse sums of fineH.
//   grid.sync
//   phase 3: block 0 reduces per-block (chi,tot) tallies, verifies
//     chi < k <= chi+tot, coarse+fine descending scans -> exact threshold.
//   grid.sync
//   phase 4: each wave scatters its own LDS candidates >= T to out.
// Registers (wcnt) and LDS candidates persist across grid syncs, so the old
// 21 MB global candidate arena + wavecnt/blkchi arrays + 3 extra dispatches
// are gone. Exact gated fallback (proven radix select) still covers arbitrary
// inputs if the bracket or an LDS buffer ever fails verification.

#define SEL_T 256

constexpr unsigned LO_BITS = 0x3F6147AEu;        // bits(0.88f)
constexpr unsigned HI_BITS = 0x3F6B851Fu;        // bits(0.92f)
constexpr unsigned NKEY    = HI_BITS - LO_BITS;  // 671089 bracket bit patterns
constexpr int      NCB     = (NKEY + 1023) / 1024;   // 656 coarse bins

constexpr int P_GRID = 1024;                 // co-resident: 4 blocks/CU x 256 CU
constexpr int P_BLK  = 256;
constexpr int P_WPB  = P_BLK / 64;           // 4 waves/block
constexpr int CAPW   = 512;                  // LDS slots/wave (mean ~174, 26 sigma)

constexpr int NBIN1   = 4096;                // fallback: bits[30:19]
constexpr int NFINE   = 1 << 19;
constexpr int NCOARSE = 512;
constexpr int F_GRID  = 256;                 // fallback grids (never hot)
constexpr int F_BLK   = 256;

// state slots
#define S_PREF 0
#define S_K1   1
#define S_T    2
#define S_FLAG 3   // nonzero -> fallback chain active

__device__ __forceinline__ bool gate_skip(const unsigned* state, int gate) {
    if (gate == 0) return false;
    unsigned fl = state[S_FLAG];
    return (gate == 1) ? (fl == 0u) : (fl != 0u);
}

// ---------------- descending 1-chunk-per-SEL_T select over a histogram ----------------
__device__ void select_desc(const unsigned* __restrict__ hist, int nbins,
                            unsigned k, unsigned* s_scan, int* s_res)
{
    int tid = threadIdx.x;
    if (tid == 0) { s_res[0] = -1; s_res[1] = 0; }
    __syncthreads();
    unsigned running = 0;
    for (int top = nbins; top > 0; top -= SEL_T) {
        int bin = top - 1 - tid;
        unsigned v = (bin >= 0) ? hist[bin] : 0u;
        s_scan[tid] = v;
        __syncthreads();
        for (int off = 1; off < SEL_T; off <<= 1) {
            unsigned add = (tid >= off) ? s_scan[tid - off] : 0u;
            __syncthreads();
            s_scan[tid] += add;
            __syncthreads();
        }
        unsigned p     = s_scan[tid];
        unsigned pprev = (tid > 0) ? s_scan[tid - 1] : 0u;
        unsigned total = s_scan[SEL_T - 1];
        __syncthreads();
        if (running + total >= k) {
            if (bin >= 0 && running + p >= k && running + pprev < k) {
                s_res[0] = bin;
                s_res[1] = (int)(k - running - pprev);
            }
            __syncthreads();
            return;
        }
        running += total;
    }
    __syncthreads();
}

// ---------------- fused fast path (cooperative) ----------------
__global__ __launch_bounds__(P_BLK, 4)
void fused_fast(const uint4* __restrict__ x, long long n4,
                uint4* __restrict__ out,
                unsigned* __restrict__ fineH, unsigned* __restrict__ coarseH,
                uint2* __restrict__ blkstat, unsigned* __restrict__ state,
                unsigned k)
{
    typedef unsigned uv4 __attribute__((ext_vector_type(4)));
    cg::grid_group grid = cg::this_grid();

    __shared__ uint2 scand[P_WPB][CAPW];          // 16 KB candidate store
    __shared__ unsigned s_scan[SEL_T];
    __shared__ int s_res[2];
    __shared__ unsigned s_w[P_WPB * 2];
    __shared__ unsigned long long s_red[P_WPB][2];
    __shared__ unsigned s_kp;
    __shared__ int s_bad;

    const int lane = threadIdx.x & 63;
    const int wid  = threadIdx.x >> 6;
    uint2* my = scand[wid];
    const unsigned long long lt = (1ull << lane) - 1ull;

    // ---- phase 1: partition stream ----
    unsigned wcnt = 0;          // wave-uniform candidate count
    unsigned chi  = 0;          // per-thread >=HI tally
    const long long stride = (long long)gridDim.x * P_BLK;
#pragma unroll 4
    for (long long i = (long long)blockIdx.x * P_BLK + threadIdx.x; i < n4; i += stride) {
        uint4 v;
        *(uv4*)&v = __builtin_nontemporal_load((const uv4*)(x + i));
        uint4 r;
        unsigned idx0 = (unsigned)(i << 2);
#define DO_COMP(c, off)                                                        \
        { unsigned b = v.c, u = b & 0x7FFFFFFFu;                               \
          bool kp = (u >= HI_BITS);                                            \
          bool cd = (u >= LO_BITS) & !kp;                                      \
          chi += (unsigned)kp;                                                 \
          r.c = kp ? b : 0u;                                                   \
          unsigned long long m = __ballot(cd);                                 \
          if (cd) {                                                            \
              atomicAdd(&fineH[u - LO_BITS], 1u);  /* fire-and-forget */       \
              unsigned pos = wcnt + (unsigned)__popcll(m & lt);                \
              if (pos < (unsigned)CAPW) my[pos] = make_uint2(b, idx0 + off);   \
          }                                                                    \
          wcnt += (unsigned)__popcll(m); }
        DO_COMP(x, 0) DO_COMP(y, 1) DO_COMP(z, 2) DO_COMP(w, 3)
#undef DO_COMP
        __builtin_nontemporal_store(*(uv4*)&r, (uv4*)(out + i));
    }

    for (int m = 32; m; m >>= 1) chi += __shfl_xor(chi, m, 64);
    if (lane == 0) {
        s_w[wid]         = chi;
        s_w[P_WPB + wid] = (wcnt < (unsigned)CAPW) ? wcnt : (unsigned)CAPW;
        if (wcnt > (unsigned)CAPW) atomicOr(&state[S_FLAG], 1u);
    }
    __syncthreads();
    if (threadIdx.x == 0) {
        unsigned a = 0, b = 0;
        for (int w = 0; w < P_WPB; ++w) { a += s_w[w]; b += s_w[P_WPB + w]; }
        blkstat[blockIdx.x] = make_uint2(a, b);
    }

    grid.sync();

    // ---- phase 2: coarse reduce (blocks 0..NCB-1) ----
    if (blockIdx.x < (unsigned)NCB) {
        unsigned base = (unsigned)blockIdx.x << 10;
        unsigned s = 0;
        for (int t = threadIdx.x; t < 1024; t += P_BLK) {
            unsigned key = base + t;
            s += (key < NKEY) ? fineH[key] : 0u;
        }
        for (int m = 32; m; m >>= 1) s += __shfl_xor(s, m, 64);
        if (lane == 0) s_w[wid] = s;
        __syncthreads();
        if (threadIdx.x == 0)
            coarseH[blockIdx.x] = s_w[0] + s_w[1] + s_w[2] + s_w[3];
    }

    grid.sync();

    // ---- phase 3: block 0 verifies + selects exact threshold ----
    if (blockIdx.x == 0 && state[S_FLAG] == 0) {
        unsigned long long chiT = 0, totT = 0;
        for (int i = threadIdx.x; i < P_GRID; i += P_BLK) {
            uint2 e = blkstat[i]; chiT += e.x; totT += e.y;
        }
        for (int m = 32; m; m >>= 1) {
            chiT += __shfl_xor(chiT, m, 64);
            totT += __shfl_xor(totT, m, 64);
        }
        if (lane == 0) { s_red[wid][0] = chiT; s_red[wid][1] = totT; }
        __syncthreads();
        if (threadIdx.x == 0) {
            unsigned long long C = 0, Tt = 0;
            for (int w = 0; w < P_WPB; ++w) { C += s_red[w][0]; Tt += s_red[w][1]; }
            if (C >= (unsigned long long)k || C + Tt < (unsigned long long)k) {
                state[S_FLAG] = 1u;  // threshold outside bracket -> exact fallback
                s_bad = 1;
            } else { s_bad = 0; s_kp = (unsigned)((unsigned long long)k - C); }
        }
        __syncthreads();
        if (!s_bad) {
            select_desc(coarseH, NCB, s_kp, s_scan, s_res);
            int cb      = s_res[0];
            unsigned r  = (unsigned)s_res[1];
            __syncthreads();
            int nfine = (int)NKEY - cb * 1024;
            if (nfine > 1024) nfine = 1024;
            select_desc(fineH + (size_t)cb * 1024, nfine, r, s_scan, s_res);
            if (threadIdx.x == 0)
                state[S_T] = LO_BITS + (unsigned)(cb * 1024 + s_res[0]);
        }
    }

    grid.sync();

    // ---- phase 4: scatter own LDS candidates >= T ----
    if (state[S_FLAG] == 0) {
        unsigned T = state[S_T];
        unsigned cnt = (wcnt < (unsigned)CAPW) ? wcnt : (unsigned)CAPW;
        float* outF = (float*)out;
        for (unsigned j = (unsigned)lane; j < cnt; j += 64) {
            uint2 e = my[j];
            if ((e.x & 0x7FFFFFFFu) >= T)
                outF[e.y] = __uint_as_float(e.x);
        }
    }
}

// ---------------- gated exact fallback (never hot; correctness only) ----------------
__global__ __launch_bounds__(F_BLK)
void f_hist1(const uint4* __restrict__ x, long long n4, unsigned* __restrict__ histA,
             const unsigned* __restrict__ state, int gate)
{
    if (gate_skip(state, gate)) return;
    __shared__ unsigned h[NBIN1];
    for (int i = threadIdx.x; i < NBIN1; i += F_BLK) h[i] = 0u;
    __syncthreads();
    long long stride = (long long)gridDim.x * F_BLK;
    for (long long i = (long long)blockIdx.x * F_BLK + threadIdx.x; i < n4; i += stride) {
        uint4 v = x[i];
        atomicAdd(&h[(v.x & 0x7FFFFFFFu) >> 19], 1u);
        atomicAdd(&h[(v.y & 0x7FFFFFFFu) >> 19], 1u);
        atomicAdd(&h[(v.z & 0x7FFFFFFFu) >> 19], 1u);
        atomicAdd(&h[(v.w & 0x7FFFFFFFu) >> 19], 1u);
    }
    __syncthreads();
    for (int i = threadIdx.x; i < NBIN1; i += F_BLK)
        if (h[i]) atomicAdd(&histA[i], h[i]);
}

__global__ __launch_bounds__(SEL_T)
void f_select1(const unsigned* __restrict__ histA, unsigned* __restrict__ state,
               unsigned k, int gate)
{
    if (gate_skip(state, gate)) return;
    __shared__ unsigned s_scan[SEL_T];
    __shared__ int s_res[2];
    select_desc(histA, NBIN1, k, s_scan, s_res);
    if (threadIdx.x == 0) {
        state[S_PREF] = (s_res[0] < 0) ? 0u : (unsigned)s_res[0];
        state[S_K1]   = (s_res[0] < 0) ? 1u : (unsigned)s_res[1];
    }
}

__global__ __launch_bounds__(F_BLK)
void f_hist2(const uint4* __restrict__ x, long long n4, const unsigned* __restrict__ state,
             unsigned* __restrict__ fineB, unsigned* __restrict__ coarseB, int gate)
{
    if (gate_skip(state, gate)) return;
    __shared__ unsigned hc[NCOARSE];
    for (int i = threadIdx.x; i < NCOARSE; i += F_BLK) hc[i] = 0u;
    __syncthreads();
    unsigned pref = state[S_PREF];
    long long stride = (long long)gridDim.x * F_BLK;
    for (long long i = (long long)blockIdx.x * F_BLK + threadIdx.x; i < n4; i += stride) {
        uint4 v = x[i];
        unsigned u;
#define DO_C(c) u = v.c & 0x7FFFFFFFu;                                        \
        if ((u >> 19) == pref) {                                              \
            atomicAdd(&fineB[u & (NFINE - 1)], 1u);                           \
            atomicAdd(&hc[(u & (NFINE - 1)) >> 10], 1u); }
        DO_C(x) DO_C(y) DO_C(z) DO_C(w)
#undef DO_C
    }
    __syncthreads();
    for (int i = threadIdx.x; i < NCOARSE; i += F_BLK)
        if (hc[i]) atomicAdd(&coarseB[i], hc[i]);
}

__global__ __launch_bounds__(SEL_T)
void f_select2(const unsigned* __restrict__ fineB, const unsigned* __restrict__ coarseB,
               unsigned* __restrict__ state, int gate)
{
    if (gate_skip(state, gate)) return;
    __shared__ unsigned s_scan[SEL_T];
    __shared__ int s_res[2];
    unsigned pref = state[S_PREF];
    unsigned k    = state[S_K1];
    select_desc(coarseB, NCOARSE, k, s_scan, s_res);
    int c       = (s_res[0] < 0) ? 0 : s_res[0];
    unsigned k1 = (s_res[0] < 0) ? 1u : (unsigned)s_res[1];
    __syncthreads();
    select_desc(fineB + (size_t)c * 1024, 1024, k1, s_scan, s_res);
    int f = (s_res[0] < 0) ? 0 : s_res[0];
    if (threadIdx.x == 0)
        state[S_T] = (pref << 19) | ((unsigned)c << 10) | (unsigned)f;
}

__global__ __launch_bounds__(256)
void f_mask(const uint4* __restrict__ x, uint4* __restrict__ out, long long n4,
            const unsigned* __restrict__ state, int gate)
{
    if (gate_skip(state, gate)) return;
    unsigned t = state[S_T];
    long long stride = (long long)gridDim.x * 256;
    for (long long i = (long long)blockIdx.x * 256 + threadIdx.x; i < n4; i += stride) {
        uint4 v = x[i];
        uint4 r;
        r.x = ((v.x & 0x7FFFFFFFu) >= t) ? v.x : 0u;
        r.y = ((v.y & 0x7FFFFFFFu) >= t) ? v.y : 0u;
        r.z = ((v.z & 0x7FFFFFFFu) >= t) ? v.z : 0u;
        r.w = ((v.w & 0x7FFFFFFFu) >= t) ? v.w : 0u;
        out[i] = r;
    }
}

// ---------------- host ----------------
extern "C" void kernel_launch(void* const* d_in, const int* in_sizes, int n_in,
                              void* d_out, int out_size, void* d_ws, size_t ws_size,
                              hipStream_t stream)
{
    long long n = (long long)in_sizes[0];
    if (n <= 0) return;
    long long n4 = n >> 2;   // n = 4*4096*2048, divisible by 4

    const double FRACTION = 1.0 / 2.718281828459045;   // matches Python 1.0/math.e
    long long k = (long long)((double)n * FRACTION);
    if (k < 1) k = 1;

    // contiguous zero region, then non-zeroed buffers
    const size_t off_state   = 0;                                   // 64 B
    const size_t off_fineH   = 64;
    const size_t off_coarseH = off_fineH   + (((size_t)NKEY * 4 + 63) & ~63ull);
    const size_t off_fineB   = off_coarseH + (((size_t)NCB * 4 + 63) & ~63ull);
    const size_t off_coarseB = off_fineB   + (size_t)NFINE * 4;
    const size_t off_histA   = off_coarseB + (size_t)NCOARSE * 4;
    const size_t zero_end    = off_histA   + (size_t)NBIN1 * 4;     // ~4.8 MB
    const size_t off_blkst   = zero_end;
    const size_t need_fast   = off_blkst + (size_t)P_GRID * 8;      // ~4.8 MB
    const size_t need_fb     = zero_end;

    uint8_t* base;
    unsigned* state = (unsigned*)d_ws;
    bool fast;
    if (ws_size >= need_fast)     { base = (uint8_t*)d_ws;  fast = true;  }
    else if (ws_size >= need_fb)  { base = (uint8_t*)d_ws;  fast = false; }
    else                          { base = (uint8_t*)d_out; fast = false;   // stage in d_out
                                    state = (unsigned*)d_ws; }

    unsigned* fineH   = (unsigned*)(base + off_fineH);
    unsigned* coarseH = (unsigned*)(base + off_coarseH);
    unsigned* fineB   = (unsigned*)(base + off_fineB);
    unsigned* coarseB = (unsigned*)(base + off_coarseB);
    unsigned* histA   = (unsigned*)(base + off_histA);
    uint2*    blkstat = (uint2*)   (base + off_blkst);

    const uint4* x = (const uint4*)d_in[0];

    if (fast) {
        // single memset: state + fineH + coarseH + fineB + coarseB + histA
        hipMemsetAsync(base, 0, zero_end, stream);

        const uint4* xp = x;
        long long    n4v = n4;
        uint4*       outp = (uint4*)d_out;
        unsigned*    fineHp = fineH;
        unsigned*    coarseHp = coarseH;
        uint2*       blkstp = blkstat;
        unsigned*    statep = state;
        unsigned     kv = (unsigned)k;
        void* args[] = { (void*)&xp, (void*)&n4v, (void*)&outp, (void*)&fineHp,
                         (void*)&coarseHp, (void*)&blkstp, (void*)&statep, (void*)&kv };
        hipLaunchCooperativeKernel((void*)fused_fast, dim3(P_GRID), dim3(P_BLK),
                                   args, 0, stream);

        // gated exact fallback — all no-ops unless verification failed
        f_hist1  <<<F_GRID, F_BLK, 0, stream>>>(x, n4, histA, state, 1);
        f_select1<<<1, SEL_T, 0, stream>>>(histA, state, (unsigned)k, 1);
        f_hist2  <<<F_GRID, F_BLK, 0, stream>>>(x, n4, state, fineB, coarseB, 1);
        f_select2<<<1, SEL_T, 0, stream>>>(fineB, coarseB, state, 1);
        f_mask   <<<1024, 256, 0, stream>>>(x, (uint4*)d_out, n4, state, 1);
    } else {
        if (state == (unsigned*)d_ws && base != (uint8_t*)d_ws)
            hipMemsetAsync(state, 0, 64, stream);
        hipMemsetAsync(base + off_fineB, 0,
                       ((size_t)NFINE + NCOARSE + NBIN1) * 4, stream);
        if (base == (uint8_t*)d_ws) hipMemsetAsync(state, 0, 64, stream);
        f_hist1  <<<F_GRID, F_BLK, 0, stream>>>(x, n4, histA, state, 0);
        f_select1<<<1, SEL_T, 0, stream>>>(histA, state, (unsigned)k, 0);
        f_hist2  <<<F_GRID, F_BLK, 0, stream>>>(x, n4, state, fineB, coarseB, 0);
        f_select2<<<1, SEL_T, 0, stream>>>(fineB, coarseB, state, 0);
        f_mask   <<<1024, 256, 0, stream>>>(x, (uint4*)d_out, n4, state, 0);
    }
}

// Round 2
// 304.483 us; speedup vs baseline: 2.0327x; 2.0327x over previous
//
#include <hip/hip_runtime.h>
#include <stdint.h>
#include <string.h>

// BoltzmannGateSTE: out = x * (|x| >= T), T = k-th largest |x|, k = int(n/e).
// Fast path = ONE full read + ONE full write + ~20 MB side traffic:
//   pass_partition: stream x -> out with bracket [LO,HI) = [0.88,0.92):
//     u >= HI -> keep, count chi;  u < LO -> zero;
//     else candidate -> placeholder 0, ballot-compacted append (bits,idx) to a
//     per-wave buffer, and ONE fire-and-forget global atomicAdd into an exact
//     per-bit-pattern count table fineH[u - LO] (671K entries, ~1 hit/bin ->
//     no contention, no LDS, no waitcnt in the hot loop).
//   coarse_reduce: 656-bin coarse sums of fineH (non-atomic).
//   fast_select (1 block): reduce tallies, verify chi < k <= chi+tot, coarse
//     descending scan then fine descending scan -> exact threshold bits.
//   cand_fixup: grid-stride over the candidate arena, write entries >= T.
// R2 change vs R0: select_desc scan is now wave-level __shfl_up (6 shuffle
// steps, 0 barriers) + 16-entry wave-total combine (2 barriers/chunk) instead
// of Hillis-Steele (30 block barriers/chunk). Semantics identical.
// R1 fused-cooperative experiment REVERTED: it serialized the streaming loop
// (VGPR=12, 600 GB/s, 392 us) -- see session journal.
// Exact gated fallback (proven R1 radix select) covers arbitrary inputs if the
// bracket or a wave buffer ever fails verification (deterministically never for
// this input; margins ~120 sigma). All logic device-side (graph capture).

#define SEL_T 1024
constexpr int SEL_W = SEL_T / 64;            // 16 waves

constexpr unsigned LO_BITS = 0x3F6147AEu;        // bits(0.88f)
constexpr unsigned HI_BITS = 0x3F6B851Fu;        // bits(0.92f)
constexpr unsigned NKEY    = HI_BITS - LO_BITS;  // 671089 bracket bit patterns
constexpr int      NCB     = (NKEY + 1023) / 1024;   // 656 coarse bins

constexpr int P_GRID = 4096;                 // partition geometry
constexpr int P_BLK  = 256;
constexpr int P_WPB  = P_BLK / 64;           // 4 waves/block
constexpr int NWAVES = P_GRID * P_WPB;       // 16384
constexpr int CAPW   = 128;                  // slots/wave (mean ~43, 13 sigma)

constexpr int NBIN1   = 4096;                // fallback: bits[30:19]
constexpr int NFINE   = 1 << 19;
constexpr int NCOARSE = 512;
constexpr int F_GRID  = 256;                 // fallback grids (never hot)
constexpr int F_BLK   = 256;

// state slots
#define S_PREF 0
#define S_K1   1
#define S_T    2
#define S_FLAG 3   // nonzero -> fallback chain active

__device__ __forceinline__ bool gate_skip(const unsigned* state, int gate) {
    if (gate == 0) return false;
    unsigned fl = state[S_FLAG];
    return (gate == 1) ? (fl == 0u) : (fl != 0u);
}

// ---------------- fast path ----------------
__global__ __launch_bounds__(P_BLK, 8)
void pass_partition(const uint4* __restrict__ x, long long n4,
                    uint4* __restrict__ out, uint2* __restrict__ cand,
                    unsigned* __restrict__ wavecnt, unsigned* __restrict__ blkchi,
                    unsigned* __restrict__ fineH, unsigned* __restrict__ state)
{
    typedef unsigned uv4 __attribute__((ext_vector_type(4)));
    const int lane  = threadIdx.x & 63;
    const int wid   = threadIdx.x >> 6;
    const int gwave = blockIdx.x * P_WPB + wid;
    uint2* my = cand + (size_t)gwave * CAPW;
    const unsigned long long lt = (1ull << lane) - 1ull;

    unsigned wcnt = 0;          // wave-uniform candidate count
    unsigned chi  = 0;          // per-thread >=HI tally
    const long long stride = (long long)gridDim.x * P_BLK;
#pragma unroll 2
    for (long long i = (long long)blockIdx.x * P_BLK + threadIdx.x; i < n4; i += stride) {
        uint4 v = x[i];
        uint4 r;
        unsigned idx0 = (unsigned)(i << 2);
#define DO_COMP(c, off)                                                        \
        { unsigned b = v.c, u = b & 0x7FFFFFFFu;                               \
          bool kp = (u >= HI_BITS);                                            \
          bool cd = (u >= LO_BITS) & !kp;                                      \
          chi += (unsigned)kp;                                                 \
          r.c = kp ? b : 0u;                                                   \
          unsigned long long m = __ballot(cd);                                 \
          if (cd) {                                                            \
              atomicAdd(&fineH[u - LO_BITS], 1u);  /* fire-and-forget */       \
              unsigned pos = wcnt + (unsigned)__popcll(m & lt);                \
              if (pos < (unsigned)CAPW) my[pos] = make_uint2(b, idx0 + off);   \
          }                                                                    \
          wcnt += (unsigned)__popcll(m); }
        DO_COMP(x, 0) DO_COMP(y, 1) DO_COMP(z, 2) DO_COMP(w, 3)
#undef DO_COMP
        __builtin_nontemporal_store(*(uv4*)&r, (uv4*)(out + i));
    }

    for (int m = 32; m; m >>= 1) chi += __shfl_xor(chi, m, 64);
    __shared__ unsigned s_chi[P_WPB];
    if (lane == 0) {
        s_chi[wid] = chi;
        wavecnt[gwave] = (wcnt < (unsigned)CAPW) ? wcnt : (unsigned)CAPW;
        if (wcnt > (unsigned)CAPW) atomicOr(&state[S_FLAG], 1u);
    }
    __syncthreads();
    if (threadIdx.x == 0) {
        unsigned a = 0;
        for (int w = 0; w < P_WPB; ++w) a += s_chi[w];
        blkchi[blockIdx.x] = a;
    }
}

// 656 blocks x 64: coarseH[b] = sum of fineH[b*1024 .. +1023]
__global__ __launch_bounds__(64)
void coarse_reduce(const unsigned* __restrict__ fineH, unsigned* __restrict__ coarseH)
{
    unsigned base = blockIdx.x << 10;
    unsigned s = 0;
    for (int t = threadIdx.x; t < 1024; t += 64) {
        unsigned key = base + t;
        s += (key < NKEY) ? fineH[key] : 0u;
    }
    for (int m = 32; m; m >>= 1) s += __shfl_xor(s, m, 64);
    if (threadIdx.x == 0) coarseH[blockIdx.x] = s;
}

// ---------------- descending 1-chunk-per-1024 select over a histogram ----------------
// Wave-level shuffle scan: 6 shfl steps + 2 block barriers per chunk
// (was: 10-step Hillis-Steele with ~30 block barriers per chunk).
__device__ void select_desc(const unsigned* __restrict__ hist, int nbins,
                            unsigned k, unsigned* s_wsum, int* s_res)
{
    const int tid  = threadIdx.x;
    const int lane = tid & 63;
    const int wid  = tid >> 6;
    if (tid == 0) { s_res[0] = -1; s_res[1] = 0; }
    __syncthreads();
    unsigned running = 0;
    for (int top = nbins; top > 0; top -= SEL_T) {
        int bin = top - 1 - tid;
        unsigned v = (bin >= 0) ? hist[bin] : 0u;
        // inclusive scan over tid order within the wave
        unsigned p = v;
#pragma unroll
        for (int off = 1; off < 64; off <<= 1) {
            unsigned t = __shfl_up(p, off, 64);
            if (lane >= off) p += t;
        }
        if (lane == 63) s_wsum[wid] = p;
        __syncthreads();
        unsigned wpref = 0, total = 0;
#pragma unroll
        for (int w = 0; w < SEL_W; ++w) {
            unsigned ws = s_wsum[w];
            wpref += (w < wid) ? ws : 0u;
            total += ws;
        }
        unsigned incl = wpref + p;      // inclusive prefix over whole block
        unsigned excl = incl - v;       // exclusive prefix
        if (running + total >= k) {     // block-uniform condition
            if (bin >= 0 && running + incl >= k && running + excl < k) {
                s_res[0] = bin;
                s_res[1] = (int)(k - running - excl);
            }
            __syncthreads();
            return;
        }
        running += total;
        __syncthreads();                // s_wsum reuse safety
    }
    __syncthreads();
}

// 1 block: tally-reduce + verify + coarse scan + fine scan -> exact T
__global__ __launch_bounds__(SEL_T)
void fast_select(const unsigned* __restrict__ blkchi, const unsigned* __restrict__ wavecnt,
                 const unsigned* __restrict__ coarseH, const unsigned* __restrict__ fineH,
                 unsigned* __restrict__ state, unsigned k)
{
    if (state[S_FLAG]) return;   // wave-buffer overflow in partition
    __shared__ unsigned s_wsum[SEL_W];
    __shared__ int s_res[2];
    __shared__ unsigned long long s_red[SEL_W][2];
    __shared__ unsigned s_kp;
    __shared__ int s_bad;

    unsigned long long chi = 0, tot = 0;
    for (int i = threadIdx.x; i < P_GRID; i += SEL_T) chi += blkchi[i];
    for (int i = threadIdx.x; i < NWAVES; i += SEL_T) tot += wavecnt[i];
    for (int m = 32; m; m >>= 1) {
        chi += __shfl_xor(chi, m, 64);
        tot += __shfl_xor(tot, m, 64);
    }
    int wid = threadIdx.x >> 6, lane = threadIdx.x & 63;
    if (lane == 0) { s_red[wid][0] = chi; s_red[wid][1] = tot; }
    __syncthreads();
    if (threadIdx.x == 0) {
        unsigned long long C = 0, Tt = 0;
        for (int w = 0; w < SEL_W; ++w) { C += s_red[w][0]; Tt += s_red[w][1]; }
        if (C >= (unsigned long long)k || C + Tt < (unsigned long long)k) {
            state[S_FLAG] = 1u;  // threshold outside bracket -> exact fallback
            s_bad = 1;
        } else { s_bad = 0; s_kp = (unsigned)((unsigned long long)k - C); }
    }
    __syncthreads();
    if (s_bad) return;
    unsigned kp = s_kp;

    select_desc(coarseH, NCB, kp, s_wsum, s_res);
    int cb      = s_res[0];
    unsigned r  = (unsigned)s_res[1];
    __syncthreads();
    int nfine = (int)NKEY - cb * 1024;
    if (nfine > 1024) nfine = 1024;
    select_desc(fineH + (size_t)cb * 1024, nfine, r, s_wsum, s_res);
    int f = s_res[0];
    if (threadIdx.x == 0)
        state[S_T] = LO_BITS + (unsigned)(cb * 1024 + f);
}

// grid-stride over the whole candidate arena; poison (0x2AAAAAAA) never passes >=T
__global__ __launch_bounds__(256)
void cand_fixup(const uint2* __restrict__ cand, const unsigned* __restrict__ state,
                float* __restrict__ out, long long n)
{
    if (state[S_FLAG]) return;
    unsigned T = state[S_T];
    long long total = (long long)NWAVES * CAPW;
    long long stride = (long long)gridDim.x * 256;
    for (long long j = (long long)blockIdx.x * 256 + threadIdx.x; j < total; j += stride) {
        uint2 e = cand[j];
        if ((e.x & 0x7FFFFFFFu) >= T && e.y < (unsigned long long)n)
            out[e.y] = __uint_as_float(e.x);
    }
}

// ---------------- gated exact fallback (never hot; correctness only) ----------------
__global__ __launch_bounds__(F_BLK)
void f_hist1(const uint4* __restrict__ x, long long n4, unsigned* __restrict__ histA,
             const unsigned* __restrict__ state, int gate)
{
    if (gate_skip(state, gate)) return;
    __shared__ unsigned h[NBIN1];
    for (int i = threadIdx.x; i < NBIN1; i += F_BLK) h[i] = 0u;
    __syncthreads();
    long long stride = (long long)gridDim.x * F_BLK;
    for (long long i = (long long)blockIdx.x * F_BLK + threadIdx.x; i < n4; i += stride) {
        uint4 v = x[i];
        atomicAdd(&h[(v.x & 0x7FFFFFFFu) >> 19], 1u);
        atomicAdd(&h[(v.y & 0x7FFFFFFFu) >> 19], 1u);
        atomicAdd(&h[(v.z & 0x7FFFFFFFu) >> 19], 1u);
        atomicAdd(&h[(v.w & 0x7FFFFFFFu) >> 19], 1u);
    }
    __syncthreads();
    for (int i = threadIdx.x; i < NBIN1; i += F_BLK)
        if (h[i]) atomicAdd(&histA[i], h[i]);
}

__global__ __launch_bounds__(SEL_T)
void f_select1(const unsigned* __restrict__ histA, unsigned* __restrict__ state,
               unsigned k, int gate)
{
    if (gate_skip(state, gate)) return;
    __shared__ unsigned s_wsum[SEL_W];
    __shared__ int s_res[2];
    select_desc(histA, NBIN1, k, s_wsum, s_res);
    if (threadIdx.x == 0) {
        state[S_PREF] = (s_res[0] < 0) ? 0u : (unsigned)s_res[0];
        state[S_K1]   = (s_res[0] < 0) ? 1u : (unsigned)s_res[1];
    }
}

__global__ __launch_bounds__(F_BLK)
void f_hist2(const uint4* __restrict__ x, long long n4, const unsigned* __restrict__ state,
             unsigned* __restrict__ fineB, unsigned* __restrict__ coarseB, int gate)
{
    if (gate_skip(state, gate)) return;
    __shared__ unsigned hc[NCOARSE];
    for (int i = threadIdx.x; i < NCOARSE; i += F_BLK) hc[i] = 0u;
    __syncthreads();
    unsigned pref = state[S_PREF];
    long long stride = (long long)gridDim.x * F_BLK;
    for (long long i = (long long)blockIdx.x * F_BLK + threadIdx.x; i < n4; i += stride) {
        uint4 v = x[i];
        unsigned u;
#define DO_C(c) u = v.c & 0x7FFFFFFFu;                                        \
        if ((u >> 19) == pref) {                                              \
            atomicAdd(&fineB[u & (NFINE - 1)], 1u);                           \
            atomicAdd(&hc[(u & (NFINE - 1)) >> 10], 1u); }
        DO_C(x) DO_C(y) DO_C(z) DO_C(w)
#undef DO_C
    }
    __syncthreads();
    for (int i = threadIdx.x; i < NCOARSE; i += F_BLK)
        if (hc[i]) atomicAdd(&coarseB[i], hc[i]);
}

__global__ __launch_bounds__(SEL_T)
void f_select2(const unsigned* __restrict__ fineB, const unsigned* __restrict__ coarseB,
               unsigned* __restrict__ state, int gate)
{
    if (gate_skip(state, gate)) return;
    __shared__ unsigned s_wsum[SEL_W];
    __shared__ int s_res[2];
    unsigned pref = state[S_PREF];
    unsigned k    = state[S_K1];
    select_desc(coarseB, NCOARSE, k, s_wsum, s_res);
    int c       = (s_res[0] < 0) ? 0 : s_res[0];
    unsigned k1 = (s_res[0] < 0) ? 1u : (unsigned)s_res[1];
    __syncthreads();
    select_desc(fineB + (size_t)c * 1024, 1024, k1, s_wsum, s_res);
    int f = (s_res[0] < 0) ? 0 : s_res[0];
    if (threadIdx.x == 0)
        state[S_T] = (pref << 19) | ((unsigned)c << 10) | (unsigned)f;
}

__global__ __launch_bounds__(256)
void f_mask(const uint4* __restrict__ x, uint4* __restrict__ out, long long n4,
            const unsigned* __restrict__ state, int gate)
{
    if (gate_skip(state, gate)) return;
    unsigned t = state[S_T];
    long long stride = (long long)gridDim.x * 256;
    for (long long i = (long long)blockIdx.x * 256 + threadIdx.x; i < n4; i += stride) {
        uint4 v = x[i];
        uint4 r;
        r.x = ((v.x & 0x7FFFFFFFu) >= t) ? v.x : 0u;
        r.y = ((v.y & 0x7FFFFFFFu) >= t) ? v.y : 0u;
        r.z = ((v.z & 0x7FFFFFFFu) >= t) ? v.z : 0u;
        r.w = ((v.w & 0x7FFFFFFFu) >= t) ? v.w : 0u;
        out[i] = r;
    }
}

// ---------------- host ----------------
extern "C" void kernel_launch(void* const* d_in, const int* in_sizes, int n_in,
                              void* d_out, int out_size, void* d_ws, size_t ws_size,
                              hipStream_t stream)
{
    long long n = (long long)in_sizes[0];
    if (n <= 0) return;
    long long n4 = n >> 2;   // n = 4*4096*2048, divisible by 4

    const double FRACTION = 1.0 / 2.718281828459045;   // matches Python 1.0/math.e
    long long k = (long long)((double)n * FRACTION);
    if (k < 1) k = 1;

    // contiguous zero region, then non-zeroed buffers
    const size_t off_state   = 0;                                   // 64 B
    const size_t off_fineH   = 64;
    const size_t off_coarseH = off_fineH   + (((size_t)NKEY * 4 + 63) & ~63ull);
    const size_t off_fineB   = off_coarseH + (((size_t)NCB * 4 + 63) & ~63ull);
    const size_t off_coarseB = off_fineB   + (size_t)NFINE * 4;
    const size_t off_histA   = off_coarseB + (size_t)NCOARSE * 4;
    const size_t zero_end    = off_histA   + (size_t)NBIN1 * 4;     // ~4.8 MB
    const size_t off_wcnt    = zero_end;
    const size_t off_bchi    = off_wcnt + (size_t)NWAVES * 4;
    const size_t off_cand    = off_bchi + (size_t)P_GRID * 4;
    const size_t need_fast   = off_cand + (size_t)NWAVES * CAPW * 8;   // ~21.2 MB
    const size_t need_fb     = zero_end;

    uint8_t* base;
    unsigned* state = (unsigned*)d_ws;
    bool fast;
    if (ws_size >= need_fast)     { base = (uint8_t*)d_ws;  fast = true;  }
    else if (ws_size >= need_fb)  { base = (uint8_t*)d_ws;  fast = false; }
    else                          { base = (uint8_t*)d_out; fast = false;   // stage in d_out
                                    state = (unsigned*)d_ws; }

    unsigned* fineH   = (unsigned*)(base + off_fineH);
    unsigned* coarseH = (unsigned*)(base + off_coarseH);
    unsigned* fineB   = (unsigned*)(base + off_fineB);
    unsigned* coarseB = (unsigned*)(base + off_coarseB);
    unsigned* histA   = (unsigned*)(base + off_histA);
    unsigned* wavecnt = (unsigned*)(base + off_wcnt);
    unsigned* blkchi  = (unsigned*)(base + off_bchi);
    uint2*    cand    = (uint2*)   (base + off_cand);

    const uint4* x = (const uint4*)d_in[0];

    if (fast) {
        // single memset: state + fineH + coarseH + fineB + coarseB + histA
        hipMemsetAsync(base, 0, zero_end, stream);
        pass_partition<<<P_GRID, P_BLK, 0, stream>>>(x, n4, (uint4*)d_out, cand,
                                                     wavecnt, blkchi, fineH, state);
        coarse_reduce <<<NCB, 64, 0, stream>>>(fineH, coarseH);
        fast_select   <<<1, SEL_T, 0, stream>>>(blkchi, wavecnt, coarseH, fineH,
                                                state, (unsigned)k);
        cand_fixup    <<<512, 256, 0, stream>>>(cand, state, (float*)d_out, n);
        // gated exact fallback — all no-ops unless verification failed
        f_hist1  <<<F_GRID, F_BLK, 0, stream>>>(x, n4, histA, state, 1);
        f_select1<<<1, SEL_T, 0, stream>>>(histA, state, (unsigned)k, 1);
        f_hist2  <<<F_GRID, F_BLK, 0, stream>>>(x, n4, state, fineB, coarseB, 1);
        f_select2<<<1, SEL_T, 0, stream>>>(fineB, coarseB, state, 1);
        f_mask   <<<1024, 256, 0, stream>>>(x, (uint4*)d_out, n4, state, 1);
    } else {
        if (state == (unsigned*)d_ws && base != (uint8_t*)d_ws)
            hipMemsetAsync(state, 0, 64, stream);
        hipMemsetAsync(base + off_fineB, 0,
                       ((size_t)NFINE + NCOARSE + NBIN1) * 4, stream);
        if (base == (uint8_t*)d_ws) hipMemsetAsync(state, 0, 64, stream);
        f_hist1  <<<F_GRID, F_BLK, 0, stream>>>(x, n4, histA, state, 0);
        f_select1<<<1, SEL_T, 0, stream>>>(histA, state, (unsigned)k, 0);
        f_hist2  <<<F_GRID, F_BLK, 0, stream>>>(x, n4, state, fineB, coarseB, 0);
        f_select2<<<1, SEL_T, 0, stream>>>(fineB, coarseB, state, 0);
        f_mask   <<<1024, 256, 0, stream>>>(x, (uint4*)d_out, n4, state, 0);
    }
}